// Round 1
// baseline (782.604 us; speedup 1.0000x reference)
//
#include <hip/hip_runtime.h>
#include <hip/hip_bf16.h>
#include <math.h>

#define B_ 2048
#define M_ 128
#define E_ 256
#define H_ 256
#define S_ 64
#define F_ 4

// ---------------------------------------------------------------------------
// Tiled fp32 GEMM: C[m,n] = sum_k A[m,k] * W[n,k]  (+ b1[n] + b2[n]) (opt tanh)
// K = 512 split into two 256 halves: A = [AL | AR], W = [WL | WR].
// GATHER: AL row m is memory[(m*M_ + rind[m])*E_ + k] (the read_ind gather).
// Tile: 64x64, 256 threads, 4x4 micro-tile, K-panel = 16.
// LDS layout [16][68]: row stride 68 floats -> store bank = (4*k + m)%32,
// 2-way max aliasing per wave (free per m136); float4 inner reads 16B-aligned.
// ---------------------------------------------------------------------------
template<bool GATHER, bool TANH>
__global__ __launch_bounds__(256) void gemm_k512(
    const float* __restrict__ AL, const float* __restrict__ AR,
    const float* __restrict__ WL, int sWL,
    const float* __restrict__ WR, int sWR,
    const float* __restrict__ b1, const float* __restrict__ b2,
    const int* __restrict__ rind, int Nfull,
    float* __restrict__ C)
{
  __shared__ float As[16][68];
  __shared__ float Bs[16][68];
  __shared__ int offL[64];

  const int t  = threadIdx.x;
  const int n0 = blockIdx.x * 64;
  const int m0 = blockIdx.y * 64;
  const int tx = t & 15;        // col group
  const int ty = t >> 4;        // row group

  if (t < 64) {
    int m = m0 + t;
    offL[t] = GATHER ? (m * M_ + rind[m]) * E_ : m * 256;
  }
  __syncthreads();

  // per-thread load rows: mrow_i = ty + 16*i (for both A-tile and W-tile), k = tx
  int offA[4], rowAR[4], rowW[4];
  #pragma unroll
  for (int i = 0; i < 4; ++i) {
    int mr   = ty + 16 * i;
    offA[i]  = offL[mr];
    rowAR[i] = (m0 + mr) * 256;
    rowW[i]  = (n0 + mr);
  }

  float acc[4][4];
  #pragma unroll
  for (int i = 0; i < 4; ++i)
    #pragma unroll
    for (int j = 0; j < 4; ++j) acc[i][j] = 0.f;

  for (int p = 0; p < 32; ++p) {
    const int k0 = p * 16;
    const bool left = (k0 < 256);
    const int kk = left ? (k0 + tx) : (k0 - 256 + tx);
    #pragma unroll
    for (int i = 0; i < 4; ++i) {
      int mr = ty + 16 * i;
      float av = left ? AL[offA[i] + kk] : AR[rowAR[i] + kk];
      float bv = left ? WL[rowW[i] * sWL + kk] : WR[rowW[i] * sWR + kk];
      As[tx][mr] = av;
      Bs[tx][mr] = bv;
    }
    __syncthreads();
    #pragma unroll
    for (int k = 0; k < 16; ++k) {
      float4 a4 = *(const float4*)&As[k][ty * 4];
      float4 b4 = *(const float4*)&Bs[k][tx * 4];
      float av[4] = {a4.x, a4.y, a4.z, a4.w};
      float bv[4] = {b4.x, b4.y, b4.z, b4.w};
      #pragma unroll
      for (int i = 0; i < 4; ++i)
        #pragma unroll
        for (int j = 0; j < 4; ++j)
          acc[i][j] = fmaf(av[i], bv[j], acc[i][j]);
    }
    __syncthreads();
  }

  // epilogue: bias + optional tanh, float4 stores
  #pragma unroll
  for (int i = 0; i < 4; ++i) {
    int row = m0 + ty * 4 + i;
    float4 o;
    float* op = (float*)&o;
    #pragma unroll
    for (int j = 0; j < 4; ++j) {
      int col = n0 + tx * 4 + j;
      float v = acc[i][j];
      if (b1) v += b1[col];
      if (b2) v += b2[col];
      if (TANH) v = tanhf(v);
      op[j] = v;
    }
    *(float4*)&C[(long)row * Nfull + n0 + tx * 4] = o;
  }
}

// ---------------------------------------------------------------------------
// LSTM elementwise: gates (B,1024) layout [i|f|g|o], -> h,c (and o_ws = h(+skip))
// ---------------------------------------------------------------------------
__global__ __launch_bounds__(256) void lstm_act(
    const float* __restrict__ gates, const float* __restrict__ c_in,
    const float* __restrict__ skip,   // nullptr for layer 0
    float* __restrict__ h_out, float* __restrict__ c_out,
    float* __restrict__ o_ws)
{
  int idx = blockIdx.x * 256 + threadIdx.x;   // B_*H_ threads
  int b = idx >> 8, hh = idx & 255;
  long base = (long)b * 1024;
  float gi = gates[base + hh];
  float gf = gates[base + 256 + hh];
  float gg = gates[base + 512 + hh];
  float go = gates[base + 768 + hh];
  float i_ = 1.f / (1.f + __expf(-gi));
  float f_ = 1.f / (1.f + __expf(-gf));
  float o_ = 1.f / (1.f + __expf(-go));
  float g_ = tanhf(gg);
  float c  = f_ * c_in[idx] + i_ * g_;
  float h  = o_ * tanhf(c);
  h_out[idx] = h;
  c_out[idx] = c;
  o_ws[idx]  = skip ? (h + skip[idx]) : h;
}

// ---------------------------------------------------------------------------
// Attention: per-batch block. scores = keys . o1, softmax (masked), ctx = p.V
// ---------------------------------------------------------------------------
__global__ __launch_bounds__(256) void attention(
    const float* __restrict__ keys, const float* __restrict__ values,
    const float* __restrict__ qmask, const float* __restrict__ o1,
    float* __restrict__ ctx)
{
  int b = blockIdx.x;
  __shared__ float o1s[256];
  __shared__ float ps[64];
  int t = threadIdx.x;
  o1s[t] = o1[b * 256 + t];
  __syncthreads();
  int w = t >> 6, l = t & 63;
  float4 o4 = *(const float4*)&o1s[l * 4];
  for (int s = w; s < 64; s += 4) {
    float4 kv = *(const float4*)&keys[(long)(b * 64 + s) * 256 + l * 4];
    float d = kv.x * o4.x + kv.y * o4.y + kv.z * o4.z + kv.w * o4.w;
    #pragma unroll
    for (int off = 32; off; off >>= 1) d += __shfl_xor(d, off);
    if (l == 0) ps[s] = d;
  }
  __syncthreads();
  if (w == 0) {
    float sc = (qmask[b * 64 + l] > 0.f) ? ps[l] : -INFINITY;
    float mx = sc;
    #pragma unroll
    for (int off = 32; off; off >>= 1) mx = fmaxf(mx, __shfl_xor(mx, off));
    float e = __expf(sc - mx);
    float sm = e;
    #pragma unroll
    for (int off = 32; off; off >>= 1) sm += __shfl_xor(sm, off);
    ps[l] = e / sm;
  }
  __syncthreads();
  float acc = 0.f;
  #pragma unroll 8
  for (int s = 0; s < 64; ++s)
    acc += ps[s] * values[(long)(b * 64 + s) * 256 + t];
  ctx[b * 256 + t] = acc;
}

// ---------------------------------------------------------------------------
// Finalize: logits[b,m] = memory[b,m,:].att_t[b,:] + of[b,m,:].W_of
//           memory_t = memory (+ att_t at write_ind row)
// Block = 4 waves = 4 rows of one batch b; wave per row; float4 per lane.
// ---------------------------------------------------------------------------
__global__ __launch_bounds__(256) void finalize(
    const float* __restrict__ memory, const float* __restrict__ of,
    const float* __restrict__ W_of, const float* __restrict__ att_t,
    const int* __restrict__ wind,
    float* __restrict__ logits, float* __restrict__ mem_out)
{
  int blk = blockIdx.x;          // B_*M_/4
  int b = blk >> 5;              // 32 blocks per batch (M_/4)
  int mg = blk & 31;
  __shared__ float ats[256];
  int t = threadIdx.x;
  ats[t] = att_t[b * 256 + t];
  __syncthreads();
  int w = t >> 6, l = t & 63;
  int m = mg * 4 + w;
  long rowbase = ((long)(b * M_ + m)) * 256;
  float4 v  = *(const float4*)&memory[rowbase + l * 4];
  float4 a4 = *(const float4*)&ats[l * 4];
  float d = v.x * a4.x + v.y * a4.y + v.z * a4.z + v.w * a4.w;
  #pragma unroll
  for (int off = 32; off; off >>= 1) d += __shfl_xor(d, off);
  int wi = wind[b];
  if (wi >= 0 && m == wi) {
    v.x += a4.x; v.y += a4.y; v.z += a4.z; v.w += a4.w;
  }
  *(float4*)&mem_out[rowbase + l * 4] = v;
  if (l == 0) {
    const float* ofp = &of[(long)(b * M_ + m) * 4];
    d += ofp[0] * W_of[0] + ofp[1] * W_of[1] + ofp[2] * W_of[2] + ofp[3] * W_of[3];
    logits[b * M_ + m] = d;
  }
}

// ---------------------------------------------------------------------------
extern "C" void kernel_launch(void* const* d_in, const int* in_sizes, int n_in,
                              void* d_out, int out_size, void* d_ws, size_t ws_size,
                              hipStream_t stream) {
  const float* memory = (const float*)d_in[0];
  const float* h0     = (const float*)d_in[1];
  const float* c0     = (const float*)d_in[2];
  const float* h1     = (const float*)d_in[3];
  const float* c1     = (const float*)d_in[4];
  const float* keys   = (const float*)d_in[5];
  const float* values = (const float*)d_in[6];
  const float* qmask  = (const float*)d_in[7];
  const float* offeat = (const float*)d_in[8];
  const float* W_ih0  = (const float*)d_in[9];
  const float* W_hh0  = (const float*)d_in[10];
  const float* b_ih0  = (const float*)d_in[11];
  const float* b_hh0  = (const float*)d_in[12];
  const float* W_ih1  = (const float*)d_in[13];
  const float* W_hh1  = (const float*)d_in[14];
  const float* b_ih1  = (const float*)d_in[15];
  const float* b_hh1  = (const float*)d_in[16];
  const float* W_att  = (const float*)d_in[17];
  const float* W_of   = (const float*)d_in[18];
  const int*   rind   = (const int*)d_in[19];
  const int*   wind   = (const int*)d_in[20];

  // workspace layout (floats)
  float* ws     = (float*)d_ws;
  float* gates0 = ws;                         // B*1024
  float* gates1 = gates0 + (size_t)B_ * 1024; // B*1024
  float* o0     = gates1 + (size_t)B_ * 1024; // B*256
  float* o1     = o0 + (size_t)B_ * 256;
  float* ctx    = o1 + (size_t)B_ * 256;
  float* att_t  = ctx + (size_t)B_ * 256;

  // output layout (floats)
  float* out     = (float*)d_out;
  float* logits  = out;                                   // B*M
  float* mem_out = logits + (size_t)B_ * M_;              // B*M*E
  float* h0n     = mem_out + (size_t)B_ * M_ * E_;        // B*H
  float* c0n     = h0n + (size_t)B_ * H_;
  float* h1n     = c0n + (size_t)B_ * H_;
  float* c1n     = h1n + (size_t)B_ * H_;

  dim3 blk(256);

  // 1) layer-0 gates: [gather(memory) | h0] @ [W_ih0 | W_hh0]^T + biases
  gemm_k512<true, false><<<dim3(1024 / 64, B_ / 64), blk, 0, stream>>>(
      memory, h0, W_ih0, 256, W_hh0, 256, b_ih0, b_hh0, rind, 1024, gates0);
  // 2) layer-0 activations
  lstm_act<<<dim3(B_ * H_ / 256), blk, 0, stream>>>(gates0, c0, nullptr, h0n, c0n, o0);
  // 3) layer-1 gates
  gemm_k512<false, false><<<dim3(1024 / 64, B_ / 64), blk, 0, stream>>>(
      o0, h1, W_ih1, 256, W_hh1, 256, b_ih1, b_hh1, nullptr, 1024, gates1);
  // 4) layer-1 activations + skip -> o1
  lstm_act<<<dim3(B_ * H_ / 256), blk, 0, stream>>>(gates1, c1, o0, h1n, c1n, o1);
  // 5) attention -> ctx
  attention<<<dim3(B_), blk, 0, stream>>>(keys, values, qmask, o1, ctx);
  // 6) att_t = tanh([o1|ctx] @ W_att^T)
  gemm_k512<false, true><<<dim3(256 / 64, B_ / 64), blk, 0, stream>>>(
      o1, ctx, W_att, 512, W_att + 256, 512, nullptr, nullptr, nullptr, 256, att_t);
  // 7) logits + memory copy/scatter
  finalize<<<dim3(B_ * M_ / 4), blk, 0, stream>>>(
      memory, offeat, W_of, att_t, wind, logits, mem_out);
}